// Round 8
// baseline (847.665 us; speedup 1.0000x reference)
//
#include <hip/hip_runtime.h>

#define NTOK 512
#define CS 384
#define CZ 128
#define CH 16
#define HN 12
#define FEAT_DIM 2112   // HN * 176
#define HSEG 176        // 16 + 24 + 8 + 128

// ---------------------------------------------------------------------------
// K1: projections + frame transform fused.
// grid (64 token-groups of 8, 2 halves): y=0 -> q,k,v scalar (576 cols);
// y=1 -> point projections (576 cols) + local->global frame in-block.
// ksT/kgT transposed [c][m]; V written as VT[480][m] (rows = h*40+j).
// ---------------------------------------------------------------------------
__global__ __launch_bounds__(256) void k_projframe(
    const float* __restrict__ s,
    const float* __restrict__ trans,
    const float* __restrict__ rot,
    const float* __restrict__ Wq,  const float* __restrict__ bq,
    const float* __restrict__ Wk,  const float* __restrict__ bk,
    const float* __restrict__ Wv,  const float* __restrict__ bv,
    const float* __restrict__ Wqp, const float* __restrict__ bqp,
    const float* __restrict__ Wkp, const float* __restrict__ bkp,
    const float* __restrict__ Wvp, const float* __restrict__ bvp,
    float* __restrict__ qs, float* __restrict__ ksT,
    float* __restrict__ qg, float* __restrict__ kgT,
    float* __restrict__ VT, float* __restrict__ transT)
{
    __shared__ float s_l[8 * CS];      // 12 KB
    __shared__ float raw_l[8 * 576];   // 18 KB (y=1 only)
    __shared__ float Rt_l[8][12];      // frames (y=1 only)
    const int t  = threadIdx.x;
    const int n0 = blockIdx.x * 8;
    const int half = blockIdx.y;

    const float4* sg  = (const float4*)(s + (size_t)n0 * CS);
    float4*       sl4 = (float4*)s_l;
#pragma unroll
    for (int j = 0; j < 3; ++j) sl4[j * 256 + t] = sg[j * 256 + t];
    if (half == 1 && t < 96) {
        const int tok = t / 12, r = t % 12;
        if (r < 9) Rt_l[tok][r] = rot[(size_t)(n0 + tok) * 9 + r];
        else       Rt_l[tok][r] = trans[(size_t)(n0 + tok) * 3 + (r - 9)];
    }
    __syncthreads();

    for (int c = t; c < 576; c += 256) {
        const float* W; const float* bp; int lc, nc;
        if (half == 0) {
            if (c < 192)      { W = Wq; bp = bq; lc = c;       }
            else if (c < 384) { W = Wk; bp = bk; lc = c - 192; }
            else              { W = Wv; bp = bv; lc = c - 384; }
            nc = 192;
        } else {
            if (c < 144)      { W = Wqp; bp = bqp; lc = c;       nc = 144; }
            else if (c < 288) { W = Wkp; bp = bkp; lc = c - 144; nc = 144; }
            else              { W = Wvp; bp = bvp; lc = c - 288; nc = 288; }
        }
        float a[8];
        const float bias = bp[lc];
#pragma unroll
        for (int i = 0; i < 8; ++i) a[i] = bias;
        const float* Wp = W + lc;
#pragma unroll 8
        for (int k = 0; k < CS; ++k) {
            float w = Wp[(size_t)k * nc];
#pragma unroll
            for (int i = 0; i < 8; ++i) a[i] += s_l[i * CS + k] * w;
        }
        if (half == 0) {
            if (c < 192) {
#pragma unroll
                for (int i = 0; i < 8; ++i) qs[(size_t)(n0 + i) * 192 + lc] = a[i];
            } else if (c < 384) {
                float* p = ksT + (size_t)lc * NTOK + n0;
#pragma unroll
                for (int i = 0; i < 8; ++i) p[i] = a[i];
            } else {
                const int vrow = (lc >> 4) * 40 + (lc & 15);
                float* p = VT + (size_t)vrow * NTOK + n0;
#pragma unroll
                for (int i = 0; i < 8; ++i) p[i] = a[i];
            }
        } else {
#pragma unroll
            for (int i = 0; i < 8; ++i) raw_l[i * 576 + c] = a[i];
        }
    }

    if (half == 1) {
        __syncthreads();
        // frame: out_i = sum_j R[i][j] x_j + t_i for 8 tokens x 576 elems
        for (int f = t; f < 8 * 576; f += 256) {
            const int tok = f / 576, loc = f % 576;
            const int i = loc % 3, base = loc - i;
            const float* x = &raw_l[tok * 576 + base];
            const float* R = &Rt_l[tok][i * 3];
            float v = Rt_l[tok][9 + i] + R[0] * x[0] + R[1] * x[1] + R[2] * x[2];
            const int n = n0 + tok;
            if (loc < 144)      qg[(size_t)n * 144 + loc] = v;
            else if (loc < 288) kgT[(size_t)(loc - 144) * NTOK + n] = v;
            else {
                const int pc = loc - 288;   // 0..287
                const int vrow = (pc / 24) * 40 + 16 + (pc % 24);
                VT[(size_t)vrow * NTOK + n] = v;
            }
        }
        if (t < 24) {
            const int tok = t % 8, i = t / 8;
            transT[(size_t)i * NTOK + n0 + tok] = trans[(size_t)(n0 + tok) * 3 + i];
        }
    }
}

// ---------------------------------------------------------------------------
// K2: mega kernel, block per n. Phases:
//  P1 bias = z@Wb (z staged b128, Wb via wave-uniform scalar loads)
//  P2 logits (+point/dist/multiscale), P3 softmax (per-wave, shfl)
//  P4 out = attn@VT (global streams + shfl reduce)
//  P5 pair_feat = attn^T@z (z direct global coalesced, att b128 broadcast)
//  P6 epilogue: frame^T, norms, feats write
// ---------------------------------------------------------------------------
__global__ __launch_bounds__(256) void k_mega(
    const float* __restrict__ z,
    const float* __restrict__ qs, const float* __restrict__ ksT,
    const float* __restrict__ qg, const float* __restrict__ kgT,
    const float* __restrict__ VT,
    const float* __restrict__ trans, const float* __restrict__ transT,
    const float* __restrict__ rot,
    const float* __restrict__ Wb, const float* __restrict__ bbv,
    const float* __restrict__ emb, const float* __restrict__ slog,
    const float* __restrict__ hw,
    float* __restrict__ feats)
{
    __shared__ float att[HN * NTOK];     // 24 KB: bias -> logits -> attn
    __shared__ float scratch[64 * 133];  // 34 KB: z-stage (P1) / pf merge (P5)
    __shared__ float emb_l[64 * HN];     // 3 KB
    __shared__ float q_l[192], qg_l[144];
    __shared__ float ph_l[36], hw_l[HN], bb_l[HN];
    __shared__ float Rl[9], tl[3];
    __shared__ float outl[480];
    const int n = blockIdx.x, t = threadIdx.x;

    // ---- P0: small loads
    for (int i = t; i < 64 * HN; i += 256) emb_l[i] = emb[i];
    if (t < 192) q_l[t] = qs[(size_t)n * 192 + t];
    if (t < 144) qg_l[t] = qg[(size_t)n * 144 + t];
    if (t < HN) {
        bb_l[t] = bbv[t]; hw_l[t] = hw[t];
        float s0 = slog[t], s1 = slog[HN + t], s2 = slog[2 * HN + t];
        float mx = fmaxf(s0, fmaxf(s1, s2));
        float e0 = expf(s0 - mx), e1 = expf(s1 - mx), e2 = expf(s2 - mx);
        float iv = 1.f / (e0 + e1 + e2);
        ph_l[t] = e0 * iv; ph_l[HN + t] = e1 * iv; ph_l[2 * HN + t] = e2 * iv;
    }
    if (t < 9) Rl[t] = rot[(size_t)n * 9 + t];
    if (t >= 16 && t < 19) tl[t - 16] = trans[(size_t)n * 3 + (t - 16)];
    __syncthreads();

    // ---- P1: bias, 8 chunks of 64 m
    {
        const int m1  = t & 63;
        const int hg1 = __builtin_amdgcn_readfirstlane(t >> 6);
        const float* wbp = Wb + hg1 * 3;   // wave-uniform -> scalar loads
        for (int ch = 0; ch < 8; ++ch) {
            const int mb = ch * 64;
            if (ch) __syncthreads();
            // stage 64 m x 128 c, coalesced float4
#pragma unroll
            for (int j = 0; j < 8; ++j) {
                const int f = t + j * 256;
                const int row = f >> 5, c4 = f & 31;
                float4 v = *(const float4*)&z[((size_t)n * NTOK + mb + row) * CZ + c4 * 4];
                float* d = &scratch[row * 133 + c4 * 4];
                d[0] = v.x; d[1] = v.y; d[2] = v.z; d[3] = v.w;
            }
            __syncthreads();
            float a0 = 0.f, a1 = 0.f, a2 = 0.f;
            const float* zr = &scratch[m1 * 133];
#pragma unroll 4
            for (int c4 = 0; c4 < 32; ++c4) {
                float4 zq = *(const float4*)&zr[c4 * 4];
                const float zs[4] = {zq.x, zq.y, zq.z, zq.w};
#pragma unroll
                for (int e = 0; e < 4; ++e) {
                    const float* w = wbp + (c4 * 4 + e) * HN;
                    a0 += zs[e] * w[0];
                    a1 += zs[e] * w[1];
                    a2 += zs[e] * w[2];
                }
            }
            att[(hg1 * 3 + 0) * NTOK + mb + m1] = a0 + bb_l[hg1 * 3 + 0];
            att[(hg1 * 3 + 1) * NTOK + mb + m1] = a1 + bb_l[hg1 * 3 + 1];
            att[(hg1 * 3 + 2) * NTOK + mb + m1] = a2 + bb_l[hg1 * 3 + 2];
        }
    }
    __syncthreads();

    // ---- P2: logits
#pragma unroll
    for (int r = 0; r < 2; ++r) {
        const int m = t + r * 256;
        const float dx = tl[0] - transT[m];
        const float dy = tl[1] - transT[NTOK + m];
        const float dz = tl[2] - transT[2 * NTOK + m];
        const float dist = sqrtf(dx * dx + dy * dy + dz * dz);
        int bin = (int)ceilf(dist * 2.f) - 1;
        bin = min(63, max(0, bin));
        const bool in0 = (dist <= 5.f), in1 = (dist > 5.f && dist <= 15.f);
        for (int h = 0; h < HN; ++h) {
            float sc = 0.f;
#pragma unroll
            for (int c = 0; c < CH; ++c)
                sc += q_l[h * CH + c] * ksT[(size_t)(h * CH + c) * NTOK + m];
            float sd = 0.f;
#pragma unroll
            for (int i = 0; i < 12; ++i) {
                float d = qg_l[h * 12 + i] - kgT[(size_t)(h * 12 + i) * NTOK + m];
                sd += d * d;
            }
            float ms = ph_l[2 * HN + h] + (in0 ? ph_l[h] : 0.f) + (in1 ? ph_l[HN + h] : 0.f);
            att[h * NTOK + m] = sc * 0.25f - 0.5f * sd * hw_l[h]
                              + att[h * NTOK + m] + emb_l[bin * HN + h] + ms;
        }
    }
    __syncthreads();

    // ---- P3: softmax, wave w owns heads 3w..3w+2
    {
        const int wv = t >> 6, lane = t & 63;
        for (int u = 0; u < 3; ++u) {
            const int h = wv * 3 + u;
            float v[8]; float mx = -1e30f;
#pragma unroll
            for (int k = 0; k < 8; ++k) { v[k] = att[h * NTOK + lane + 64 * k]; mx = fmaxf(mx, v[k]); }
#pragma unroll
            for (int off = 32; off; off >>= 1) mx = fmaxf(mx, __shfl_xor(mx, off));
            float sm = 0.f;
#pragma unroll
            for (int k = 0; k < 8; ++k) { v[k] = expf(v[k] - mx); sm += v[k]; }
#pragma unroll
            for (int off = 32; off; off >>= 1) sm += __shfl_xor(sm, off);
            const float inv = 1.f / sm;
#pragma unroll
            for (int k = 0; k < 8; ++k) att[h * NTOK + lane + 64 * k] = v[k] * inv;
        }
    }
    __syncthreads();

    // ---- P4: out = attn @ VT (480 rows), wave w owns heads 3w..3w+2
    {
        const int wv = __builtin_amdgcn_readfirstlane(t >> 6);
        const int lane = t & 63;
        for (int u = 0; u < 3; ++u) {
            const int h = wv * 3 + u;
            float av[8];
#pragma unroll
            for (int k = 0; k < 8; ++k) av[k] = att[h * NTOK + lane + 64 * k];
            for (int j = 0; j < 40; ++j) {
                const float* vrow = VT + (size_t)(h * 40 + j) * NTOK + lane;
                float a = 0.f;
#pragma unroll
                for (int k = 0; k < 8; ++k) a += av[k] * vrow[64 * k];
#pragma unroll
                for (int off = 32; off; off >>= 1) a += __shfl_down(a, off);
                if (lane == 0) outl[h * 40 + j] = a;
            }
        }
    }

    // ---- P5: pair_feat = attn^T @ z, 4-way m-slab split
    {
        const int slab = t >> 6;                 // wave id
        const int lane = t & 63;
        const int hgp  = lane >> 5;              // 0/1 -> heads 0-5 / 6-11
        const int cq   = lane & 31;              // c quad
        float acc[6][4];
#pragma unroll
        for (int u = 0; u < 6; ++u)
#pragma unroll
            for (int v = 0; v < 4; ++v) acc[u][v] = 0.f;
        const int mbase = slab * 128;
        for (int m4 = 0; m4 < 128; m4 += 4) {
            float4 a4[6];
#pragma unroll
            for (int u = 0; u < 6; ++u)
                a4[u] = *(const float4*)&att[(hgp * 6 + u) * NTOK + mbase + m4];
#pragma unroll
            for (int mi = 0; mi < 4; ++mi) {
                const int m = mbase + m4 + mi;
                float4 zq = *(const float4*)&z[((size_t)n * NTOK + m) * CZ + cq * 4];
                const float zs[4] = {zq.x, zq.y, zq.z, zq.w};
#pragma unroll
                for (int u = 0; u < 6; ++u) {
                    const float am = ((const float*)&a4[u])[mi];
#pragma unroll
                    for (int v = 0; v < 4; ++v) acc[u][v] += am * zs[v];
                }
            }
        }
        // write slab partials into scratch[slab][12][128]
#pragma unroll
        for (int u = 0; u < 6; ++u) {
            float* p = &scratch[slab * 1536 + (hgp * 6 + u) * CZ + cq * 4];
            p[0] = acc[u][0]; p[1] = acc[u][1]; p[2] = acc[u][2]; p[3] = acc[u][3];
        }
    }
    __syncthreads();

    // ---- P6: merge pf + epilogue
    for (int f = t; f < HN * CZ; f += 256) {
        const int h = f >> 7, c = f & 127;
        float sum = scratch[f] + scratch[1536 + f] + scratch[3072 + f] + scratch[4608 + f];
        feats[(size_t)n * FEAT_DIM + h * HSEG + 48 + c] = sum;
    }
    for (int f = t; f < 576; f += 256) {
        const int h = f / 48, j = f % 48;
        const float* sh = &outl[h * 40];
        float* fp = feats + (size_t)n * FEAT_DIM + h * HSEG;
        if (j < 16) {
            fp[j] = sh[j];
        } else if (j < 40) {
            const int jj = j - 16, p = jj / 3, i = jj % 3;
            float val = 0.f;
#pragma unroll
            for (int q = 0; q < 3; ++q) val += Rl[q * 3 + i] * (sh[16 + p * 3 + q] - tl[q]);
            fp[16 + jj] = val;
        } else {
            const int p = j - 40;
            float s2 = 0.f;
#pragma unroll
            for (int i = 0; i < 3; ++i) {
                float val = 0.f;
#pragma unroll
                for (int q = 0; q < 3; ++q) val += Rl[q * 3 + i] * (sh[16 + p * 3 + q] - tl[q]);
                s2 += val * val;
            }
            fp[40 + p] = sqrtf(s2);
        }
    }
}

// ---------------------------------------------------------------------------
// K3: out = feats @ Wout + bout  (f32, tiled K-split GEMM, atomic epilogue)
// ---------------------------------------------------------------------------
#define KT 16
__global__ __launch_bounds__(256) void k_outproj(
    const float* __restrict__ feats,
    const float* __restrict__ Wout,
    const float* __restrict__ bout,
    float* __restrict__ out)
{
    __shared__ float As[KT][64];   // As[k][row]
    __shared__ float Bs[KT][64];   // Bs[k][col]
    const int t  = threadIdx.x;
    const int n0 = blockIdx.x * 64;
    const int j0 = blockIdx.y * 64;
    const int k0 = blockIdx.z * HSEG;

    const int arow = t >> 2, akq = (t & 3) * 4;      // A: row, k-quad
    const int bkk  = t >> 4, bjq = (t & 15) * 4;     // B: k, col-quad
    const int tr   = t >> 4, tc  = t & 15;           // C: 4x4 tile coords

    float acc[4][4] = {{0.f}};
    for (int s = 0; s < 11; ++s) {
        const int ks = k0 + s * KT;
        float4 a4 = *(const float4*)&feats[(size_t)(n0 + arow) * FEAT_DIM + ks + akq];
        float4 b4 = *(const float4*)&Wout[(size_t)(ks + bkk) * 384 + j0 + bjq];
        __syncthreads();   // previous step's LDS reads complete
        As[akq + 0][arow] = a4.x;
        As[akq + 1][arow] = a4.y;
        As[akq + 2][arow] = a4.z;
        As[akq + 3][arow] = a4.w;
        *(float4*)&Bs[bkk][bjq] = b4;
        __syncthreads();
#pragma unroll
        for (int kk = 0; kk < KT; ++kk) {
            float4 av = *(const float4*)&As[kk][tr * 4];
            float4 bv = *(const float4*)&Bs[kk][tc * 4];
            acc[0][0] += av.x * bv.x; acc[0][1] += av.x * bv.y;
            acc[0][2] += av.x * bv.z; acc[0][3] += av.x * bv.w;
            acc[1][0] += av.y * bv.x; acc[1][1] += av.y * bv.y;
            acc[1][2] += av.y * bv.z; acc[1][3] += av.y * bv.w;
            acc[2][0] += av.z * bv.x; acc[2][1] += av.z * bv.y;
            acc[2][2] += av.z * bv.z; acc[2][3] += av.z * bv.w;
            acc[3][0] += av.w * bv.x; acc[3][1] += av.w * bv.y;
            acc[3][2] += av.w * bv.z; acc[3][3] += av.w * bv.w;
        }
    }

    const bool addb = (blockIdx.z == 0);
#pragma unroll
    for (int i = 0; i < 4; ++i) {
        const int row = n0 + tr * 4 + i;
#pragma unroll
        for (int jj = 0; jj < 4; ++jj) {
            const int col = j0 + tc * 4 + jj;
            float v = acc[i][jj];
            if (addb) v += bout[col];
            atomicAdd(&out[(size_t)row * 384 + col], v);
        }
    }
}

// ---------------------------------------------------------------------------
extern "C" void kernel_launch(void* const* d_in, const int* in_sizes, int n_in,
                              void* d_out, int out_size, void* d_ws, size_t ws_size,
                              hipStream_t stream) {
    const float* s     = (const float*)d_in[0];
    const float* z     = (const float*)d_in[1];
    const float* trans = (const float*)d_in[2];
    const float* rot   = (const float*)d_in[3];
    const float* Wq    = (const float*)d_in[4];
    const float* bq    = (const float*)d_in[5];
    const float* Wk    = (const float*)d_in[6];
    const float* bk    = (const float*)d_in[7];
    const float* Wv    = (const float*)d_in[8];
    const float* bv    = (const float*)d_in[9];
    const float* Wqp   = (const float*)d_in[10];
    const float* bqp   = (const float*)d_in[11];
    const float* Wkp   = (const float*)d_in[12];
    const float* bkp   = (const float*)d_in[13];
    const float* Wvp   = (const float*)d_in[14];
    const float* bvp   = (const float*)d_in[15];
    const float* Wb    = (const float*)d_in[16];
    const float* bb    = (const float*)d_in[17];
    const float* emb   = (const float*)d_in[18];
    const float* slog  = (const float*)d_in[19];
    const float* hw    = (const float*)d_in[20];
    const float* Wout  = (const float*)d_in[21];
    const float* bout  = (const float*)d_in[22];

    float* W = (float*)d_ws;
    float* qs     = W;                    // 512*192 = 98304
    float* ksT    = qs + 98304;           // 192*512 = 98304
    float* qg     = ksT + 98304;          // 512*144 = 73728
    float* kgT    = qg + 73728;           // 144*512 = 73728
    float* VT     = kgT + 73728;          // 480*512 = 245760
    float* transT = VT + 245760;          // 3*512   = 1536
    float* feats  = transT + 1536;        // 512*2112 = 1081344
    // total ~1.67M floats = 6.7 MB

    k_projframe<<<dim3(64, 2), 256, 0, stream>>>(
        s, trans, rot, Wq, bq, Wk, bk, Wv, bv,
        Wqp, bqp, Wkp, bkp, Wvp, bvp,
        qs, ksT, qg, kgT, VT, transT);
    k_mega<<<512, 256, 0, stream>>>(
        z, qs, ksT, qg, kgT, VT, trans, transT, rot,
        Wb, bb, emb, slog, hw, feats);
    hipMemsetAsync(d_out, 0, (size_t)NTOK * 384 * sizeof(float), stream);
    k_outproj<<<dim3(8, 6, 12), 256, 0, stream>>>(feats, Wout, bout, (float*)d_out);
}